// Round 7
// baseline (377.001 us; speedup 1.0000x reference)
//
#include <hip/hip_runtime.h>
#include <math.h>

#define BB 8
#define NN 4096
#define CC 640
#define SS 77
#define XDIM 768
#define HH 8
#define DH 80
#define BETA 0.5f
#define TAU 0.1f
#define EPSV 1e-8f

typedef _Float16 half_t;
typedef _Float16 h8 __attribute__((ext_vector_type(8)));
typedef _Float16 h4v __attribute__((ext_vector_type(4)));
typedef float f4 __attribute__((ext_vector_type(4)));

// =======================================================================
// K1: all weight packing + erase_pre, merged. (R5-passing version)
// =======================================================================
__global__ __launch_bounds__(256) void wpack_all(const float* __restrict__ Wk,
                                                 const float* __restrict__ Wv,
                                                 const float* __restrict__ Wq,
                                                 const float* __restrict__ Wo,
                                                 const float* __restrict__ target,
                                                 const float* __restrict__ anchor,
                                                 const float* __restrict__ pres,
                                                 half_t* __restrict__ pW,
                                                 half_t* __restrict__ pWq,
                                                 half_t* __restrict__ pWo,
                                                 float* __restrict__ u_hat,
                                                 float* __restrict__ wvec,
                                                 float* __restrict__ ginv) {
    __shared__ float redw[32];
    int blk = blockIdx.x;
    int tid = threadIdx.x;
    if (blk < 480) {
        int idx = blk * 256 + tid;
        int l = idx & 63;
        int kb = (idx >> 6) % 24;
        int nt = idx / (24 * 64);
        int n = nt * 16 + (l & 15);
        int k0 = kb * 32 + ((l >> 4) << 3);
        half_t vals[8];
#pragma unroll
        for (int j = 0; j < 8; j++) {
            float w = (n < CC) ? Wk[(size_t)(k0 + j) * CC + n]
                               : Wv[(size_t)(k0 + j) * CC + (n - CC)];
            vals[j] = (half_t)w;
        }
        *(h8*)(pW + (size_t)idx * 8) = *(h8*)vals;
        return;
    }
    blk -= 480;
    if (blk < 240) {
        // pWq[h]: B[k=d][n=c] = qs * Wq[c][80h+d], d<80 else 0
        const float qs = 0.11180339887498949f;
        int idx = blk * 256 + tid;
        int l = idx & 63;
        int kb = (idx >> 6) % 3;
        int nt = (idx / (3 * 64)) % 40;
        int h = idx / (40 * 3 * 64);
        int n = nt * 16 + (l & 15);
        int k0 = kb * 32 + ((l >> 4) << 3);
        half_t vals[8];
#pragma unroll
        for (int j = 0; j < 8; j++) {
            int d = k0 + j;
            float w = (d < DH) ? qs * Wq[(size_t)n * CC + h * DH + d] : 0.f;
            vals[j] = (half_t)w;
        }
        *(h8*)(pWq + (size_t)idx * 8) = *(h8*)vals;
        return;
    }
    blk -= 240;
    if (blk < 240) {
        // pWo[h]: B[k=d][n] = Wo[80h+d][n], d<80 else 0
        int idx = blk * 256 + tid;
        int l = idx & 63;
        int kb = (idx >> 6) % 3;
        int nt = (idx / (3 * 64)) % 40;
        int h = idx / (40 * 3 * 64);
        int n = nt * 16 + (l & 15);
        int k0 = kb * 32 + ((l >> 4) << 3);
        half_t vals[8];
#pragma unroll
        for (int j = 0; j < 8; j++) {
            int d = k0 + j;
            float w = (d < DH) ? Wo[(size_t)(h * DH + d) * CC + n] : 0.f;
            vals[j] = (half_t)w;
        }
        *(h8*)(pWo + (size_t)idx * 8) = *(h8*)vals;
        return;
    }
    blk -= 240;
    {
        int s = blk;
        int w = tid >> 6;
        const float* p0 = pres + (size_t)s * CC;
        const float* p1 = pres + (size_t)(SS + s) * CC;
        const float* tg = target + (size_t)s * CC;
        const float* an = anchor + (size_t)s * CC;
        float x0[3], x1[3], xt[3], xa[3];
        float r7[7];
#pragma unroll
        for (int k = 0; k < 7; k++) r7[k] = 0.f;
#pragma unroll
        for (int i = 0; i < 3; i++) {
            int c = tid + i * 256;
            bool ok = c < CC;
            float v0 = ok ? p0[c] : 0.f;
            float v1 = ok ? p1[c] : 0.f;
            float t = ok ? tg[c] : 0.f;
            float a = ok ? an[c] : 0.f;
            x0[i] = v0; x1[i] = v1; xt[i] = t; xa[i] = a;
            r7[0] += v0 * v0; r7[1] += v0 * v1; r7[2] += v1 * v1;
            r7[3] += v0 * t;  r7[4] += v1 * t;  r7[5] += v0 * a; r7[6] += v1 * a;
        }
#pragma unroll
        for (int k = 0; k < 7; k++)
#pragma unroll
            for (int st = 1; st < 64; st <<= 1) r7[k] += __shfl_xor(r7[k], st, 64);
        if ((tid & 63) == 0)
#pragma unroll
            for (int k = 0; k < 7; k++) redw[k * 4 + w] = r7[k];
        __syncthreads();
#pragma unroll
        for (int k = 0; k < 7; k++)
            r7[k] = redw[k * 4] + redw[k * 4 + 1] + redw[k * 4 + 2] + redw[k * 4 + 3];
        __syncthreads();
        float a00 = r7[0], a01 = r7[1], a11 = r7[2];
        float bt0 = r7[3], bt1 = r7[4], ba0 = r7[5], ba1 = r7[6];
        float det = a00 * a11 - a01 * a01;
        float i00 = a11 / det, i01 = -a01 / det, i11 = a00 / det;
        float ct0 = i00 * bt0 + i01 * bt1, ct1 = i01 * bt0 + i11 * bt1;
        float ca0 = i00 * ba0 + i01 * ba1, ca1 = i01 * ba0 + i11 * ba1;
        float ud[3], ad[3], at[3];
        float r2[2];
        r2[0] = 0.f; r2[1] = 0.f;
#pragma unroll
        for (int i = 0; i < 3; i++) {
            ud[i] = xt[i] - ct0 * x0[i] - ct1 * x1[i];
            ad[i] = xa[i] - ca0 * x0[i] - ca1 * x1[i];
            r2[0] += ud[i] * ud[i]; r2[1] += ud[i] * ad[i];
        }
#pragma unroll
        for (int k = 0; k < 2; k++)
#pragma unroll
            for (int st = 1; st < 64; st <<= 1) r2[k] += __shfl_xor(r2[k], st, 64);
        if ((tid & 63) == 0) { redw[w] = r2[0]; redw[4 + w] = r2[1]; }
        __syncthreads();
        r2[0] = redw[0] + redw[1] + redw[2] + redw[3];
        r2[1] = redw[4] + redw[5] + redw[6] + redw[7];
        __syncthreads();
        float nu = sqrtf(r2[0]) + EPSV;
        float f = r2[1] / nu;
        float na2 = 0;
#pragma unroll
        for (int i = 0; i < 3; i++) {
            at[i] = ad[i] - f * (ud[i] / nu);
            na2 += at[i] * at[i];
        }
#pragma unroll
        for (int st = 1; st < 64; st <<= 1) na2 += __shfl_xor(na2, st, 64);
        if ((tid & 63) == 0) redw[w] = na2;
        __syncthreads();
        na2 = redw[0] + redw[1] + redw[2] + redw[3];
        float nai = 1.f / (sqrtf(na2) + EPSV);
#pragma unroll
        for (int i = 0; i < 3; i++) {
            int c = tid + i * 256;
            if (c < CC) {
                float uh = ud[i] / nu;
                float ah = at[i] * nai;
                u_hat[(size_t)s * CC + c] = uh;
                wvec[(size_t)s * CC + c] = BETA * ah - uh;
            }
        }
        if (tid == 0) {
            ginv[s * 4 + 0] = i00; ginv[s * 4 + 1] = i01;
            ginv[s * 4 + 2] = i11; ginv[s * 4 + 3] = 0.f;
        }
    }
}

// ---------------- k = enc@Wk, v = enc@Wv via MFMA (M=616 rows, K=768, N=1280) ----------------
// N split 4-way: grid 39*4 = 156 blocks; float4 staging. (R5-passing version)
__global__ __launch_bounds__(256) void kv_gemm(const float* __restrict__ enc,
                                               const half_t* __restrict__ pW,
                                               float* __restrict__ kmat,
                                               float* __restrict__ vmat) {
    __shared__ half_t sA[16][776];
    int blk = blockIdx.x;
    int rb = blk % 39;
    int ns = blk / 39;            // 0..3, n-slice
    int r0 = rb * 16;
    int tid = threadIdx.x;
#pragma unroll
    for (int i = 0; i < 12; i++) {
        int idx4 = tid + i * 256;
        int f = idx4 * 4;
        int r = f / 768, c = f - r * 768;
        int bs = r0 + r;
        float4 v = (bs < BB * SS) ? *(const float4*)(enc + (size_t)bs * XDIM + c)
                                  : make_float4(0.f, 0.f, 0.f, 0.f);
        half_t hv[4];
        hv[0] = (half_t)v.x; hv[1] = (half_t)v.y; hv[2] = (half_t)v.z; hv[3] = (half_t)v.w;
        *(h4v*)&sA[r][c] = *(h4v*)hv;
    }
    __syncthreads();
    int w = tid >> 6, l = tid & 63;
    int arow = l & 15, aq = l >> 4;
    f4 acc[5];
#pragma unroll
    for (int i = 0; i < 5; i++) acc[i] = (f4){0.f, 0.f, 0.f, 0.f};
    for (int kb = 0; kb < 24; kb++) {
        h8 af = *(const h8*)&sA[arow][kb * 32 + aq * 8];
#pragma unroll
        for (int nt = 0; nt < 5; nt++) {
            int ntile = ns * 20 + w * 5 + nt;
            h8 bf = *(const h8*)(pW + ((size_t)(ntile * 24 + kb) * 64 + l) * 8);
            acc[nt] = __builtin_amdgcn_mfma_f32_16x16x32_f16(af, bf, acc[nt], 0, 0, 0);
        }
    }
#pragma unroll
    for (int nt = 0; nt < 5; nt++) {
        int col = (ns * 20 + w * 5 + nt) * 16 + arow;
#pragma unroll
        for (int i = 0; i < 4; i++) {
            int bs = r0 + aq * 4 + i;
            if (bs < BB * SS) {
                float val = acc[nt][i];
                if (col < CC) kmat[(size_t)bs * CC + col] = val;
                else          vmat[(size_t)bs * CC + (col - CC)] = val;
            }
        }
    }
}

// ---------------- apply erase to v rows (in place) ---------------- (R5)
__global__ __launch_bounds__(256) void erase_apply(float* __restrict__ vmat,
                                                   const float* __restrict__ pres,
                                                   const float* __restrict__ u_hat,
                                                   const float* __restrict__ wvec,
                                                   const float* __restrict__ ginv) {
    int tid = threadIdx.x;
    int w = tid >> 6, l = tid & 63;
    int bs = blockIdx.x * 4 + w;          // < 616
    int s = bs % SS;
    float* v = vmat + (size_t)bs * CC;
    const float* p0 = pres + (size_t)s * CC;
    const float* p1 = pres + (size_t)(SS + s) * CC;
    const float* uh = u_hat + (size_t)s * CC;
    float vv[10];
    float b0 = 0, b1 = 0, tt = 0, n2 = 0;
#pragma unroll
    for (int i = 0; i < 10; i++) {
        int c = l + i * 64;
        float x = v[c];
        vv[i] = x;
        b0 += p0[c] * x; b1 += p1[c] * x; tt += uh[c] * x; n2 += x * x;
    }
#pragma unroll
    for (int st = 1; st < 64; st <<= 1) {
        b0 += __shfl_xor(b0, st, 64);
        b1 += __shfl_xor(b1, st, 64);
        tt += __shfl_xor(tt, st, 64);
        n2 += __shfl_xor(n2, st, 64);
    }
    float i00 = ginv[s * 4], i01 = ginv[s * 4 + 1], i11 = ginv[s * 4 + 2];
    float pv2 = b0 * (i00 * b0 + i01 * b1) + b1 * (i01 * b0 + i11 * b1);
    float vf2 = n2 - pv2;
    if (vf2 < 0.f) vf2 = 0.f;
    float denom = sqrtf(vf2) + EPSV;
    if (fabsf(tt) / denom >= TAU) {
        const float* wv = wvec + (size_t)s * CC;
#pragma unroll
        for (int i = 0; i < 10; i++) {
            int c = l + i * 64;
            v[c] = vv[i] + tt * wv[c];
        }
    }
}

// =======================================================================
// K4: hsgemm — per (b,h): C[80,640] = X[80,80] @ W_h[80,640] via MFMA,
// scatter fp16 into attn B-frag streams pM / pV. (R5-passing version)
// =======================================================================
__global__ __launch_bounds__(512) void hsgemm(const float* __restrict__ kmat,
                                              const float* __restrict__ vmat,
                                              const half_t* __restrict__ pWq,
                                              const half_t* __restrict__ pWo,
                                              half_t* __restrict__ pM,
                                              half_t* __restrict__ pV) {
    __shared__ half_t sX[80][104];
    int blk = blockIdx.x;
    int b = blk & 7;
    int h = (blk >> 3) & 7;
    int job = blk >> 6;
    const float* src = job ? vmat : kmat;
    const half_t* pWx = job ? pWo : pWq;
    int tid = threadIdx.x;
    for (int e = tid; e < 80 * 104; e += 512) {
        int r = e / 104, d = e - r * 104;
        float v = 0.f;
        if (r < SS && d < DH) v = src[((size_t)b * SS + r) * CC + h * DH + d];
        sX[r][d] = (half_t)v;
    }
    __syncthreads();
    int w = tid >> 6, l = tid & 63;
    int arow = l & 15, aq = l >> 4;
    f4 acc[5][5];
#pragma unroll
    for (int mt = 0; mt < 5; mt++)
#pragma unroll
        for (int nn = 0; nn < 5; nn++) acc[mt][nn] = (f4){0.f, 0.f, 0.f, 0.f};
#pragma unroll
    for (int kb = 0; kb < 3; kb++) {
        h8 af[5];
#pragma unroll
        for (int mt = 0; mt < 5; mt++)
            af[mt] = *(const h8*)&sX[mt * 16 + arow][kb * 32 + aq * 8];
#pragma unroll
        for (int nn = 0; nn < 5; nn++) {
            int nt = w * 5 + nn;
            h8 bf = *(const h8*)(pWx + ((size_t)((h * 40 + nt) * 3 + kb) * 64 + l) * 8);
#pragma unroll
            for (int mt = 0; mt < 5; mt++)
                acc[mt][nn] = __builtin_amdgcn_mfma_f32_16x16x32_f16(af[mt], bf, acc[mt][nn], 0, 0, 0);
        }
    }
    half_t* dst = (job ? pV : pM) + (size_t)b * 409600;
    if (job == 1) {
#pragma unroll
        for (int mt = 0; mt < 5; mt++) {
#pragma unroll
            for (int nn = 0; nn < 5; nn++) {
                int na = (w * 5 + nn) * 16 + arow;      // c
                int ka0 = h * 80 + mt * 16 + aq * 4;    // i = 0
                size_t idx = ((size_t)((na >> 4) * 20 + (ka0 >> 5)) * 64 +
                              ((((ka0 >> 3) & 3) << 4) | (na & 15))) * 8 + (ka0 & 7);
                half_t tmp[4];
#pragma unroll
                for (int i = 0; i < 4; i++) {
                    int sp = mt * 16 + aq * 4 + i;
                    tmp[i] = (half_t)((sp < SS) ? acc[mt][nn][i] : 0.f);
                }
                *(h4v*)(dst + idx) = *(h4v*)tmp;
            }
        }
    } else {
#pragma unroll
        for (int mt = 0; mt < 5; mt++) {
#pragma unroll
            for (int nn = 0; nn < 5; nn++) {
#pragma unroll
                for (int i = 0; i < 4; i++) {
                    int sp = mt * 16 + aq * 4 + i;       // 0..79
                    int c = (w * 5 + nn) * 16 + arow;
                    float fv = (sp < SS) ? acc[mt][nn][i] : 0.f;
                    int na = h * 80 + sp, ka = c;
                    size_t idx = ((size_t)((na >> 4) * 20 + (ka >> 5)) * 64 +
                                  ((((ka >> 3) & 3) << 4) | (na & 15))) * 8 + (ka & 7);
                    dst[idx] = (half_t)fv;
                }
            }
        }
    }
}

// =======================================================================
// K5: fused scores -> per-head register softmax -> out GEMM. M=64 rows.
// R2/R5 skeleton (81920-B station, 2 blocks/CU, acc[4][5]) + NEW:
// unroll-by-2 DUAL-BUFFER B-prefetch, NO copies (R6's bf=bfn copy form
// spilled: WRITE_SIZE 95->239 MB). Even steps consume b0 while b1 loads;
// odd steps consume b1 while b0 loads. Peak live: 1 buffer consumed +
// 1 loading (80) + a-frags (16) + addr (~25) ~= 121 VGPR < 128 cap.
// =======================================================================
__device__ __forceinline__ half_t* sp_ptr(half_t* base, int r, int c) {
    int byte = r * 1280 + c * 2;
    byte ^= (r & 7) << 4;               // swizzle bits 4-6: spreads rows across 16B slots
    return (half_t*)((char*)base + byte);
}

__global__ __launch_bounds__(512, 4) void attn_main(const float* __restrict__ hidden,
                                                    const half_t* __restrict__ pM,
                                                    const half_t* __restrict__ pV,
                                                    const float* __restrict__ bo,
                                                    float* __restrict__ out) {
    __shared__ half_t sP[64 * 640];  // hidden stage -> P station (reused), swizzled
    int blk = blockIdx.x;
    int b = blk & 7;
    int n0 = (blk >> 3) << 6;
    int tid = threadIdx.x;
    int w = tid >> 6, l = tid & 63;   // w = head owned by this wave
    int arow = l & 15, aq = l >> 4;
    const float* Hb = hidden + ((size_t)b * NN + n0) * CC;
    const half_t* pMb = pM + (size_t)b * 409600;
    const half_t* pVb = pV + (size_t)b * 409600;

    // ---- stage hidden 64x640 -> fp16, vectorized ----
#pragma unroll
    for (int it = 0; it < 10; it++) {
        int e = (tid + it * 512) * 8;
        int r = e / 640, c = e - r * 640;
        const float* src = Hb + (size_t)r * CC + c;
        half_t v[8];
#pragma unroll
        for (int j = 0; j < 8; j++) v[j] = (half_t)src[j];
        *(h8*)sp_ptr(sP, r, c) = *(h8*)v;
    }
    __syncthreads();

    // ---- phase A: scores(head w) = H_tile @ M_b[:, w*80 : w*80+80] ----
    f4 acc[4][5];
#pragma unroll
    for (int mi = 0; mi < 4; mi++)
#pragma unroll
        for (int nt = 0; nt < 5; nt++) acc[mi][nt] = (f4){0.f, 0.f, 0.f, 0.f};
    {
        h8 b0[5], b1[5];
#pragma unroll
        for (int nt = 0; nt < 5; nt++)
            b0[nt] = *(const h8*)(pMb + ((size_t)((w * 5 + nt) * 20 + 0) * 64 + l) * 8);
#pragma unroll 1
        for (int kbg = 0; kbg < 20; kbg += 2) {
            // prefetch odd step's B-frags, then even MFMA burst
#pragma unroll
            for (int nt = 0; nt < 5; nt++)
                b1[nt] = *(const h8*)(pMb + ((size_t)((w * 5 + nt) * 20 + kbg + 1) * 64 + l) * 8);
            h8 a0[4];
#pragma unroll
            for (int mi = 0; mi < 4; mi++)
                a0[mi] = *(const h8*)sp_ptr(sP, mi * 16 + arow, kbg * 32 + aq * 8);
            __builtin_amdgcn_s_setprio(1);
#pragma unroll
            for (int nt = 0; nt < 5; nt++)
#pragma unroll
                for (int mi = 0; mi < 4; mi++)
                    acc[mi][nt] = __builtin_amdgcn_mfma_f32_16x16x32_f16(a0[mi], b0[nt], acc[mi][nt], 0, 0, 0);
            __builtin_amdgcn_s_setprio(0);
            // prefetch next even step's B-frags, then odd MFMA burst
            int k2 = (kbg + 2 < 20) ? kbg + 2 : 18;   // tail: harmless reload, unused
#pragma unroll
            for (int nt = 0; nt < 5; nt++)
                b0[nt] = *(const h8*)(pMb + ((size_t)((w * 5 + nt) * 20 + k2) * 64 + l) * 8);
            h8 a1[4];
#pragma unroll
            for (int mi = 0; mi < 4; mi++)
                a1[mi] = *(const h8*)sp_ptr(sP, mi * 16 + arow, (kbg + 1) * 32 + aq * 8);
            __builtin_amdgcn_s_setprio(1);
#pragma unroll
            for (int nt = 0; nt < 5; nt++)
#pragma unroll
                for (int mi = 0; mi < 4; mi++)
                    acc[mi][nt] = __builtin_amdgcn_mfma_f32_16x16x32_f16(a1[mi], b1[nt], acc[mi][nt], 0, 0, 0);
            __builtin_amdgcn_s_setprio(0);
        }
    }

    // ---- per-head softmax, fully in registers (one head per wave) ----
    float pmax[4][4];
#pragma unroll
    for (int mi = 0; mi < 4; mi++)
#pragma unroll
        for (int i = 0; i < 4; i++) pmax[mi][i] = -1e30f;
#pragma unroll
    for (int nt = 0; nt < 5; nt++) {
        int sl = nt * 16 + arow;
        if (sl < SS) {
#pragma unroll
            for (int mi = 0; mi < 4; mi++)
#pragma unroll
                for (int i = 0; i < 4; i++)
                    pmax[mi][i] = fmaxf(pmax[mi][i], acc[mi][nt][i]);
        }
    }
#pragma unroll
    for (int st = 1; st < 16; st <<= 1) {
#pragma unroll
        for (int mi = 0; mi < 4; mi++)
#pragma unroll
            for (int i = 0; i < 4; i++)
                pmax[mi][i] = fmaxf(pmax[mi][i], __shfl_xor(pmax[mi][i], st, 64));
    }
    float psum[4][4];
#pragma unroll
    for (int mi = 0; mi < 4; mi++)
#pragma unroll
        for (int i = 0; i < 4; i++) psum[mi][i] = 0.f;
#pragma unroll
    for (int nt = 0; nt < 5; nt++) {
        int sl = nt * 16 + arow;
        bool ok = sl < SS;
#pragma unroll
        for (int mi = 0; mi < 4; mi++)
#pragma unroll
            for (int i = 0; i < 4; i++) {
                float e = ok ? __expf(acc[mi][nt][i] - pmax[mi][i]) : 0.f;
                acc[mi][nt][i] = e;
                psum[mi][i] += e;
            }
    }
#pragma unroll
    for (int st = 1; st < 16; st <<= 1) {
#pragma unroll
        for (int mi = 0; mi < 4; mi++)
#pragma unroll
            for (int i = 0; i < 4; i++)
                psum[mi][i] += __shfl_xor(psum[mi][i], st, 64);
    }
    float rinv[4][4];
#pragma unroll
    for (int mi = 0; mi < 4; mi++)
#pragma unroll
        for (int i = 0; i < 4; i++) rinv[mi][i] = 1.f / psum[mi][i];

    __syncthreads();  // all waves done reading sP (hidden) in phase A
    // write P (fp16) into sP: cols w*80 + nt*16 + arow, rows mi*16 + aq*4 + i
#pragma unroll
    for (int mi = 0; mi < 4; mi++)
#pragma unroll
        for (int nt = 0; nt < 5; nt++) {
            int col = w * 80 + nt * 16 + arow;
#pragma unroll
            for (int i = 0; i < 4; i++) {
                int r = mi * 16 + aq * 4 + i;
                *sp_ptr(sP, r, col) = (half_t)(acc[mi][nt][i] * rinv[mi][i]);
            }
        }
    __syncthreads();

    // ---- phase B: out[:, w*80 : w*80+80] = P @ Vo_b ----
    f4 acc2[4][5];
#pragma unroll
    for (int mi = 0; mi < 4; mi++)
#pragma unroll
        for (int nt = 0; nt < 5; nt++) acc2[mi][nt] = (f4){0.f, 0.f, 0.f, 0.f};
    {
        h8 b0[5], b1[5];
#pragma unroll
        for (int nt = 0; nt < 5; nt++)
            b0[nt] = *(const h8*)(pVb + ((size_t)((w * 5 + nt) * 20 + 0) * 64 + l) * 8);
#pragma unroll 1
        for (int kb = 0; kb < 20; kb += 2) {
#pragma unroll
            for (int nt = 0; nt < 5; nt++)
                b1[nt] = *(const h8*)(pVb + ((size_t)((w * 5 + nt) * 20 + kb + 1) * 64 + l) * 8);
            h8 p0[4];
#pragma unroll
            for (int mi = 0; mi < 4; mi++)
                p0[mi] = *(const h8*)sp_ptr(sP, mi * 16 + arow, kb * 32 + aq * 8);
            __builtin_amdgcn_s_setprio(1);
#pragma unroll
            for (int nt = 0; nt < 5; nt++)
#pragma unroll
                for (int mi = 0; mi < 4; mi++)
                    acc2[mi][nt] = __builtin_amdgcn_mfma_f32_16x16x32_f16(p0[mi], b0[nt], acc2[mi][nt], 0, 0, 0);
            __builtin_amdgcn_s_setprio(0);
            int k2 = (kb + 2 < 20) ? kb + 2 : 18;     // tail: harmless reload, unused
#pragma unroll
            for (int nt = 0; nt < 5; nt++)
                b0[nt] = *(const h8*)(pVb + ((size_t)((w * 5 + nt) * 20 + k2) * 64 + l) * 8);
            h8 p1[4];
#pragma unroll
            for (int mi = 0; mi < 4; mi++)
                p1[mi] = *(const h8*)sp_ptr(sP, mi * 16 + arow, (kb + 1) * 32 + aq * 8);
            __builtin_amdgcn_s_setprio(1);
#pragma unroll
            for (int nt = 0; nt < 5; nt++)
#pragma unroll
                for (int mi = 0; mi < 4; mi++)
                    acc2[mi][nt] = __builtin_amdgcn_mfma_f32_16x16x32_f16(p1[mi], b1[nt], acc2[mi][nt], 0, 0, 0);
            __builtin_amdgcn_s_setprio(0);
        }
    }
    float* Ob = out + ((size_t)b * NN + n0) * CC;
#pragma unroll
    for (int nt = 0; nt < 5; nt++) {
        int col = (w * 5 + nt) * 16 + arow;
        float bias = bo[col];
#pragma unroll
        for (int mi = 0; mi < 4; mi++)
#pragma unroll
            for (int i = 0; i < 4; i++) {
                int r = mi * 16 + aq * 4 + i;
                Ob[(size_t)r * CC + col] = acc2[mi][nt][i] + bias;
            }
    }
}

extern "C" void kernel_launch(void* const* d_in, const int* in_sizes, int n_in,
                              void* d_out, int out_size, void* d_ws, size_t ws_size,
                              hipStream_t stream) {
    const float* hidden = (const float*)d_in[0];
    const float* enc    = (const float*)d_in[1];
    const float* Wq     = (const float*)d_in[2];
    const float* Wk     = (const float*)d_in[3];
    const float* Wv     = (const float*)d_in[4];
    const float* Wo     = (const float*)d_in[5];
    const float* bo     = (const float*)d_in[6];
    const float* target = (const float*)d_in[7];
    const float* anchor = (const float*)d_in[8];
    const float* pres   = (const float*)d_in[9];
    float* outp = (float*)d_out;
    char* ws = (char*)d_ws;

    float* u_hat = (float*)(ws + 0);          // 77*640 f32   -> 197120
    float* wvec  = (float*)(ws + 197120);     // 77*640 f32   -> 394240
    float* ginv  = (float*)(ws + 394240);     // 77*4 f32 pad -> 395520
    float* kmat  = (float*)(ws + 395520);     // 616*640 f32  -> 1972480
    float* vmat  = (float*)(ws + 1972480);    // 616*640 f32  -> 3549440
    half_t* pW   = (half_t*)(ws + 3549440);   // 768*1280 f16 -> 5515520
    half_t* pWq  = (half_t*)(ws + 5515520);   // 8*40*3*64*8  -> 6498560
    half_t* pWo  = (half_t*)(ws + 6498560);   // 8*40*3*64*8  -> 7481600
    half_t* pM   = (half_t*)(ws + 7481600);   // 8*409600 f16 -> 14035200
    half_t* pV   = (half_t*)(ws + 14035200);  // 8*409600 f16 -> 20588800

    hipLaunchKernelGGL(wpack_all, dim3(1037), dim3(256), 0, stream, Wk, Wv, Wq, Wo,
                       target, anchor, pres, pW, pWq, pWo, u_hat, wvec, ginv);
    hipLaunchKernelGGL(kv_gemm, dim3(156), dim3(256), 0, stream, enc, pW, kmat, vmat);
    hipLaunchKernelGGL(erase_apply, dim3(154), dim3(256), 0, stream, vmat, pres, u_hat,
                       wvec, ginv);
    hipLaunchKernelGGL(hsgemm, dim3(128), dim3(512), 0, stream, kmat, vmat, pWq, pWo, pM, pV);
    hipLaunchKernelGGL(attn_main, dim3(512), dim3(512), 0, stream, hidden, pM, pV, bo, outp);
}

// Round 8
// 255.868 us; speedup vs baseline: 1.4734x; 1.4734x over previous
//
#include <hip/hip_runtime.h>
#include <math.h>

#define BB 8
#define NN 4096
#define CC 640
#define SS 77
#define XDIM 768
#define HH 8
#define DH 80
#define BETA 0.5f
#define TAU 0.1f
#define EPSV 1e-8f

typedef _Float16 half_t;
typedef _Float16 h8 __attribute__((ext_vector_type(8)));
typedef _Float16 h4v __attribute__((ext_vector_type(4)));
typedef float f4 __attribute__((ext_vector_type(4)));

// =======================================================================
// K1: all weight packing + erase_pre, merged. (R5-passing version, exact)
// =======================================================================
__global__ __launch_bounds__(256) void wpack_all(const float* __restrict__ Wk,
                                                 const float* __restrict__ Wv,
                                                 const float* __restrict__ Wq,
                                                 const float* __restrict__ Wo,
                                                 const float* __restrict__ target,
                                                 const float* __restrict__ anchor,
                                                 const float* __restrict__ pres,
                                                 half_t* __restrict__ pW,
                                                 half_t* __restrict__ pWq,
                                                 half_t* __restrict__ pWo,
                                                 float* __restrict__ u_hat,
                                                 float* __restrict__ wvec,
                                                 float* __restrict__ ginv) {
    __shared__ float redw[32];
    int blk = blockIdx.x;
    int tid = threadIdx.x;
    if (blk < 480) {
        int idx = blk * 256 + tid;
        int l = idx & 63;
        int kb = (idx >> 6) % 24;
        int nt = idx / (24 * 64);
        int n = nt * 16 + (l & 15);
        int k0 = kb * 32 + ((l >> 4) << 3);
        half_t vals[8];
#pragma unroll
        for (int j = 0; j < 8; j++) {
            float w = (n < CC) ? Wk[(size_t)(k0 + j) * CC + n]
                               : Wv[(size_t)(k0 + j) * CC + (n - CC)];
            vals[j] = (half_t)w;
        }
        *(h8*)(pW + (size_t)idx * 8) = *(h8*)vals;
        return;
    }
    blk -= 480;
    if (blk < 240) {
        // pWq[h]: B[k=d][n=c] = qs * Wq[c][80h+d], d<80 else 0
        const float qs = 0.11180339887498949f;
        int idx = blk * 256 + tid;
        int l = idx & 63;
        int kb = (idx >> 6) % 3;
        int nt = (idx / (3 * 64)) % 40;
        int h = idx / (40 * 3 * 64);
        int n = nt * 16 + (l & 15);
        int k0 = kb * 32 + ((l >> 4) << 3);
        half_t vals[8];
#pragma unroll
        for (int j = 0; j < 8; j++) {
            int d = k0 + j;
            float w = (d < DH) ? qs * Wq[(size_t)n * CC + h * DH + d] : 0.f;
            vals[j] = (half_t)w;
        }
        *(h8*)(pWq + (size_t)idx * 8) = *(h8*)vals;
        return;
    }
    blk -= 240;
    if (blk < 240) {
        // pWo[h]: B[k=d][n] = Wo[80h+d][n], d<80 else 0
        int idx = blk * 256 + tid;
        int l = idx & 63;
        int kb = (idx >> 6) % 3;
        int nt = (idx / (3 * 64)) % 40;
        int h = idx / (40 * 3 * 64);
        int n = nt * 16 + (l & 15);
        int k0 = kb * 32 + ((l >> 4) << 3);
        half_t vals[8];
#pragma unroll
        for (int j = 0; j < 8; j++) {
            int d = k0 + j;
            float w = (d < DH) ? Wo[(size_t)(h * DH + d) * CC + n] : 0.f;
            vals[j] = (half_t)w;
        }
        *(h8*)(pWo + (size_t)idx * 8) = *(h8*)vals;
        return;
    }
    blk -= 240;
    {
        int s = blk;
        int w = tid >> 6;
        const float* p0 = pres + (size_t)s * CC;
        const float* p1 = pres + (size_t)(SS + s) * CC;
        const float* tg = target + (size_t)s * CC;
        const float* an = anchor + (size_t)s * CC;
        float x0[3], x1[3], xt[3], xa[3];
        float r7[7];
#pragma unroll
        for (int k = 0; k < 7; k++) r7[k] = 0.f;
#pragma unroll
        for (int i = 0; i < 3; i++) {
            int c = tid + i * 256;
            bool ok = c < CC;
            float v0 = ok ? p0[c] : 0.f;
            float v1 = ok ? p1[c] : 0.f;
            float t = ok ? tg[c] : 0.f;
            float a = ok ? an[c] : 0.f;
            x0[i] = v0; x1[i] = v1; xt[i] = t; xa[i] = a;
            r7[0] += v0 * v0; r7[1] += v0 * v1; r7[2] += v1 * v1;
            r7[3] += v0 * t;  r7[4] += v1 * t;  r7[5] += v0 * a; r7[6] += v1 * a;
        }
#pragma unroll
        for (int k = 0; k < 7; k++)
#pragma unroll
            for (int st = 1; st < 64; st <<= 1) r7[k] += __shfl_xor(r7[k], st, 64);
        if ((tid & 63) == 0)
#pragma unroll
            for (int k = 0; k < 7; k++) redw[k * 4 + w] = r7[k];
        __syncthreads();
#pragma unroll
        for (int k = 0; k < 7; k++)
            r7[k] = redw[k * 4] + redw[k * 4 + 1] + redw[k * 4 + 2] + redw[k * 4 + 3];
        __syncthreads();
        float a00 = r7[0], a01 = r7[1], a11 = r7[2];
        float bt0 = r7[3], bt1 = r7[4], ba0 = r7[5], ba1 = r7[6];
        float det = a00 * a11 - a01 * a01;
        float i00 = a11 / det, i01 = -a01 / det, i11 = a00 / det;
        float ct0 = i00 * bt0 + i01 * bt1, ct1 = i01 * bt0 + i11 * bt1;
        float ca0 = i00 * ba0 + i01 * ba1, ca1 = i01 * ba0 + i11 * ba1;
        float ud[3], ad[3], at[3];
        float r2[2];
        r2[0] = 0.f; r2[1] = 0.f;
#pragma unroll
        for (int i = 0; i < 3; i++) {
            ud[i] = xt[i] - ct0 * x0[i] - ct1 * x1[i];
            ad[i] = xa[i] - ca0 * x0[i] - ca1 * x1[i];
            r2[0] += ud[i] * ud[i]; r2[1] += ud[i] * ad[i];
        }
#pragma unroll
        for (int k = 0; k < 2; k++)
#pragma unroll
            for (int st = 1; st < 64; st <<= 1) r2[k] += __shfl_xor(r2[k], st, 64);
        if ((tid & 63) == 0) { redw[w] = r2[0]; redw[4 + w] = r2[1]; }
        __syncthreads();
        r2[0] = redw[0] + redw[1] + redw[2] + redw[3];
        r2[1] = redw[4] + redw[5] + redw[6] + redw[7];
        __syncthreads();
        float nu = sqrtf(r2[0]) + EPSV;
        float f = r2[1] / nu;
        float na2 = 0;
#pragma unroll
        for (int i = 0; i < 3; i++) {
            at[i] = ad[i] - f * (ud[i] / nu);
            na2 += at[i] * at[i];
        }
#pragma unroll
        for (int st = 1; st < 64; st <<= 1) na2 += __shfl_xor(na2, st, 64);
        if ((tid & 63) == 0) redw[w] = na2;
        __syncthreads();
        na2 = redw[0] + redw[1] + redw[2] + redw[3];
        float nai = 1.f / (sqrtf(na2) + EPSV);
#pragma unroll
        for (int i = 0; i < 3; i++) {
            int c = tid + i * 256;
            if (c < CC) {
                float uh = ud[i] / nu;
                float ah = at[i] * nai;
                u_hat[(size_t)s * CC + c] = uh;
                wvec[(size_t)s * CC + c] = BETA * ah - uh;
            }
        }
        if (tid == 0) {
            ginv[s * 4 + 0] = i00; ginv[s * 4 + 1] = i01;
            ginv[s * 4 + 2] = i11; ginv[s * 4 + 3] = 0.f;
        }
    }
}

// ---------------- k = enc@Wk, v = enc@Wv via MFMA (R5-passing, exact) ----------------
__global__ __launch_bounds__(256) void kv_gemm(const float* __restrict__ enc,
                                               const half_t* __restrict__ pW,
                                               float* __restrict__ kmat,
                                               float* __restrict__ vmat) {
    __shared__ half_t sA[16][776];
    int blk = blockIdx.x;
    int rb = blk % 39;
    int ns = blk / 39;            // 0..3, n-slice
    int r0 = rb * 16;
    int tid = threadIdx.x;
#pragma unroll
    for (int i = 0; i < 12; i++) {
        int idx4 = tid + i * 256;
        int f = idx4 * 4;
        int r = f / 768, c = f - r * 768;
        int bs = r0 + r;
        float4 v = (bs < BB * SS) ? *(const float4*)(enc + (size_t)bs * XDIM + c)
                                  : make_float4(0.f, 0.f, 0.f, 0.f);
        half_t hv[4];
        hv[0] = (half_t)v.x; hv[1] = (half_t)v.y; hv[2] = (half_t)v.z; hv[3] = (half_t)v.w;
        *(h4v*)&sA[r][c] = *(h4v*)hv;
    }
    __syncthreads();
    int w = tid >> 6, l = tid & 63;
    int arow = l & 15, aq = l >> 4;
    f4 acc[5];
#pragma unroll
    for (int i = 0; i < 5; i++) acc[i] = (f4){0.f, 0.f, 0.f, 0.f};
    for (int kb = 0; kb < 24; kb++) {
        h8 af = *(const h8*)&sA[arow][kb * 32 + aq * 8];
#pragma unroll
        for (int nt = 0; nt < 5; nt++) {
            int ntile = ns * 20 + w * 5 + nt;
            h8 bf = *(const h8*)(pW + ((size_t)(ntile * 24 + kb) * 64 + l) * 8);
            acc[nt] = __builtin_amdgcn_mfma_f32_16x16x32_f16(af, bf, acc[nt], 0, 0, 0);
        }
    }
#pragma unroll
    for (int nt = 0; nt < 5; nt++) {
        int col = (ns * 20 + w * 5 + nt) * 16 + arow;
#pragma unroll
        for (int i = 0; i < 4; i++) {
            int bs = r0 + aq * 4 + i;
            if (bs < BB * SS) {
                float val = acc[nt][i];
                if (col < CC) kmat[(size_t)bs * CC + col] = val;
                else          vmat[(size_t)bs * CC + (col - CC)] = val;
            }
        }
    }
}

// ---------------- apply erase to v rows (in place) ---------------- (R5 exact)
__global__ __launch_bounds__(256) void erase_apply(float* __restrict__ vmat,
                                                   const float* __restrict__ pres,
                                                   const float* __restrict__ u_hat,
                                                   const float* __restrict__ wvec,
                                                   const float* __restrict__ ginv) {
    int tid = threadIdx.x;
    int w = tid >> 6, l = tid & 63;
    int bs = blockIdx.x * 4 + w;          // < 616
    int s = bs % SS;
    float* v = vmat + (size_t)bs * CC;
    const float* p0 = pres + (size_t)s * CC;
    const float* p1 = pres + (size_t)(SS + s) * CC;
    const float* uh = u_hat + (size_t)s * CC;
    float vv[10];
    float b0 = 0, b1 = 0, tt = 0, n2 = 0;
#pragma unroll
    for (int i = 0; i < 10; i++) {
        int c = l + i * 64;
        float x = v[c];
        vv[i] = x;
        b0 += p0[c] * x; b1 += p1[c] * x; tt += uh[c] * x; n2 += x * x;
    }
#pragma unroll
    for (int st = 1; st < 64; st <<= 1) {
        b0 += __shfl_xor(b0, st, 64);
        b1 += __shfl_xor(b1, st, 64);
        tt += __shfl_xor(tt, st, 64);
        n2 += __shfl_xor(n2, st, 64);
    }
    float i00 = ginv[s * 4], i01 = ginv[s * 4 + 1], i11 = ginv[s * 4 + 2];
    float pv2 = b0 * (i00 * b0 + i01 * b1) + b1 * (i01 * b0 + i11 * b1);
    float vf2 = n2 - pv2;
    if (vf2 < 0.f) vf2 = 0.f;
    float denom = sqrtf(vf2) + EPSV;
    if (fabsf(tt) / denom >= TAU) {
        const float* wv = wvec + (size_t)s * CC;
#pragma unroll
        for (int i = 0; i < 10; i++) {
            int c = l + i * 64;
            v[c] = vv[i] + tt * wv[c];
        }
    }
}

// =======================================================================
// K4: hsgemm — per (b,h): C[80,640] = X[80,80] @ W_h[80,640] via MFMA.
// NEW epilogue for job0 (pM): the old path issued 100 scalar 2-B scattered
// global stores per thread. In the pM stream ka&7 is contiguous for
// consecutive c, so: stage C through LDS sC (two row-chunks, 48+32, so
// static LDS stays 78 KB < the proven-safe 81,920 B), then flush row-wise
// as h8 (16-B) stores -> 8x fewer store instructions, coalesced.
// Staging loads vectorized to float4 (d 0..79 contiguous).
// job1 (pV) keeps its h4v path (already vectorized).
// =======================================================================
__global__ __launch_bounds__(512) void hsgemm(const float* __restrict__ kmat,
                                              const float* __restrict__ vmat,
                                              const half_t* __restrict__ pWq,
                                              const half_t* __restrict__ pWo,
                                              half_t* __restrict__ pM,
                                              half_t* __restrict__ pV) {
    __shared__ half_t sX[80][104];      // 16,640 B
    __shared__ half_t sC[48][640];      // 61,440 B  (total 78,080 B)
    int blk = blockIdx.x;
    int b = blk & 7;
    int h = (blk >> 3) & 7;
    int job = blk >> 6;
    const float* src = job ? vmat : kmat;
    const half_t* pWx = job ? pWo : pWq;
    int tid = threadIdx.x;
    // stage X: 77 rows x 80 cols, float4 loads (row*640 + h*80 + d is 16-B aligned)
    for (int e = tid; e < 80 * 26; e += 512) {   // 26 float4-slots covers 104 cols
        int r = e / 26, d4 = e - r * 26;
        int d = d4 * 4;
        half_t hv[4] = {(half_t)0.f, (half_t)0.f, (half_t)0.f, (half_t)0.f};
        if (r < SS && d < DH) {
            float4 v = *(const float4*)(src + ((size_t)b * SS + r) * CC + h * DH + d);
            hv[0] = (half_t)v.x; hv[1] = (half_t)v.y; hv[2] = (half_t)v.z; hv[3] = (half_t)v.w;
        }
        *(h4v*)&sX[r][d] = *(h4v*)hv;
    }
    __syncthreads();
    int w = tid >> 6, l = tid & 63;
    int arow = l & 15, aq = l >> 4;
    f4 acc[5][5];
#pragma unroll
    for (int mt = 0; mt < 5; mt++)
#pragma unroll
        for (int nn = 0; nn < 5; nn++) acc[mt][nn] = (f4){0.f, 0.f, 0.f, 0.f};
#pragma unroll
    for (int kb = 0; kb < 3; kb++) {
        h8 af[5];
#pragma unroll
        for (int mt = 0; mt < 5; mt++)
            af[mt] = *(const h8*)&sX[mt * 16 + arow][kb * 32 + aq * 8];
#pragma unroll
        for (int nn = 0; nn < 5; nn++) {
            int nt = w * 5 + nn;
            h8 bf = *(const h8*)(pWx + ((size_t)((h * 40 + nt) * 3 + kb) * 64 + l) * 8);
#pragma unroll
            for (int mt = 0; mt < 5; mt++)
                acc[mt][nn] = __builtin_amdgcn_mfma_f32_16x16x32_f16(af[mt], bf, acc[mt][nn], 0, 0, 0);
        }
    }
    half_t* dst = (job ? pV : pM) + (size_t)b * 409600;
    if (job == 1) {
#pragma unroll
        for (int mt = 0; mt < 5; mt++) {
#pragma unroll
            for (int nn = 0; nn < 5; nn++) {
                int na = (w * 5 + nn) * 16 + arow;      // c
                int ka0 = h * 80 + mt * 16 + aq * 4;    // i = 0
                size_t idx = ((size_t)((na >> 4) * 20 + (ka0 >> 5)) * 64 +
                              ((((ka0 >> 3) & 3) << 4) | (na & 15))) * 8 + (ka0 & 7);
                half_t tmp[4];
#pragma unroll
                for (int i = 0; i < 4; i++) {
                    int sp = mt * 16 + aq * 4 + i;
                    tmp[i] = (half_t)((sp < SS) ? acc[mt][nn][i] : 0.f);
                }
                *(h4v*)(dst + idx) = *(h4v*)tmp;
            }
        }
    } else {
        // chunk 0: rows 0..47 (mt 0..2); chunk 1: rows 48..79 (mt 3..4)
#pragma unroll
        for (int ch = 0; ch < 2; ch++) {
            int mt_lo = ch ? 3 : 0;
            int mt_hi = ch ? 5 : 3;
            int rbase = ch ? 48 : 0;
            int nrows = ch ? 32 : 48;
            __syncthreads();            // sC free (prev chunk flushed / sX done)
            for (int mt = mt_lo; mt < mt_hi; mt++) {
#pragma unroll
                for (int nn = 0; nn < 5; nn++) {
                    int c = (w * 5 + nn) * 16 + arow;
#pragma unroll
                    for (int i = 0; i < 4; i++) {
                        int sp = mt * 16 + aq * 4 + i;
                        sC[sp - rbase][c] = (half_t)((sp < SS) ? acc[mt][nn][i] : 0.f);
                    }
                }
            }
            __syncthreads();
            // flush: nrows x 80 h8-groups
            for (int e = tid; e < nrows * 80; e += 512) {
                int r = e / 80, g = e - r * 80;
                int c0 = g * 8;
                int na = h * 80 + rbase + r;            // score coord
                size_t idx = ((size_t)((na >> 4) * 20 + (c0 >> 5)) * 64 +
                              ((((c0 >> 3) & 3) << 4) | (na & 15))) * 8;
                *(h8*)(dst + idx) = *(const h8*)&sC[r][c0];
            }
        }
    }
}

// =======================================================================
// K5: fused scores -> per-head register softmax -> out GEMM. M=64 rows.
// EXACT R5-passing version (94 us, MfmaUtil 24, 2 blocks/CU, no spill).
// Register-level B-prefetch is structurally dead here: acc(80, AGPR-side)
// + 64 arch VGPRs fills the 128-reg budget at 4 waves/SIMD; any extra
// B-buffer live range spills to scratch (R6: WRITE 239 MB, R7: 555 MB).
// =======================================================================
__device__ __forceinline__ half_t* sp_ptr(half_t* base, int r, int c) {
    int byte = r * 1280 + c * 2;
    byte ^= (r & 7) << 4;               // swizzle bits 4-6: spreads rows across 16B slots
    return (half_t*)((char*)base + byte);
}

__global__ __launch_bounds__(512, 4) void attn_main(const float* __restrict__ hidden,
                                                    const half_t* __restrict__ pM,
                                                    const half_t* __restrict__ pV,
                                                    const float* __restrict__ bo,
                                                    float* __restrict__ out) {
    __shared__ half_t sP[64 * 640];  // hidden stage -> P station (reused), swizzled
    int blk = blockIdx.x;
    int b = blk & 7;
    int n0 = (blk >> 3) << 6;
    int tid = threadIdx.x;
    int w = tid >> 6, l = tid & 63;   // w = head owned by this wave
    int arow = l & 15, aq = l >> 4;
    const float* Hb = hidden + ((size_t)b * NN + n0) * CC;
    const half_t* pMb = pM + (size_t)b * 409600;
    const half_t* pVb = pV + (size_t)b * 409600;

    // ---- stage hidden 64x640 -> fp16, vectorized ----
#pragma unroll
    for (int it = 0; it < 10; it++) {
        int e = (tid + it * 512) * 8;
        int r = e / 640, c = e - r * 640;
        const float* src = Hb + (size_t)r * CC + c;
        half_t v[8];
#pragma unroll
        for (int j = 0; j < 8; j++) v[j] = (half_t)src[j];
        *(h8*)sp_ptr(sP, r, c) = *(h8*)v;
    }
    __syncthreads();

    // ---- phase A: scores(head w) = H_tile @ M_b[:, w*80 : w*80+80] ----
    f4 acc[4][5];
#pragma unroll
    for (int mi = 0; mi < 4; mi++)
#pragma unroll
        for (int nt = 0; nt < 5; nt++) acc[mi][nt] = (f4){0.f, 0.f, 0.f, 0.f};
    for (int kbg = 0; kbg < 20; kbg++) {
        h8 a[4];
#pragma unroll
        for (int mi = 0; mi < 4; mi++)
            a[mi] = *(const h8*)sp_ptr(sP, mi * 16 + arow, kbg * 32 + aq * 8);
        h8 bf[5];
#pragma unroll
        for (int nt = 0; nt < 5; nt++)
            bf[nt] = *(const h8*)(pMb + ((size_t)((w * 5 + nt) * 20 + kbg) * 64 + l) * 8);
        __builtin_amdgcn_s_setprio(1);
#pragma unroll
        for (int nt = 0; nt < 5; nt++)
#pragma unroll
            for (int mi = 0; mi < 4; mi++)
                acc[mi][nt] = __builtin_amdgcn_mfma_f32_16x16x32_f16(a[mi], bf[nt], acc[mi][nt], 0, 0, 0);
        __builtin_amdgcn_s_setprio(0);
    }

    // ---- per-head softmax, fully in registers (one head per wave) ----
    float pmax[4][4];
#pragma unroll
    for (int mi = 0; mi < 4; mi++)
#pragma unroll
        for (int i = 0; i < 4; i++) pmax[mi][i] = -1e30f;
#pragma unroll
    for (int nt = 0; nt < 5; nt++) {
        int sl = nt * 16 + arow;
        if (sl < SS) {
#pragma unroll
            for (int mi = 0; mi < 4; mi++)
#pragma unroll
                for (int i = 0; i < 4; i++)
                    pmax[mi][i] = fmaxf(pmax[mi][i], acc[mi][nt][i]);
        }
    }
#pragma unroll
    for (int st = 1; st < 16; st <<= 1) {
#pragma unroll
        for (int mi = 0; mi < 4; mi++)
#pragma unroll
            for (int i = 0; i < 4; i++)
                pmax[mi][i] = fmaxf(pmax[mi][i], __shfl_xor(pmax[mi][i], st, 64));
    }
    float psum[4][4];
#pragma unroll
    for (int mi = 0; mi < 4; mi++)
#pragma unroll
        for (int i = 0; i < 4; i++) psum[mi][i] = 0.f;
#pragma unroll
    for (int nt = 0; nt < 5; nt++) {
        int sl = nt * 16 + arow;
        bool ok = sl < SS;
#pragma unroll
        for (int mi = 0; mi < 4; mi++)
#pragma unroll
            for (int i = 0; i < 4; i++) {
                float e = ok ? __expf(acc[mi][nt][i] - pmax[mi][i]) : 0.f;
                acc[mi][nt][i] = e;
                psum[mi][i] += e;
            }
    }
#pragma unroll
    for (int st = 1; st < 16; st <<= 1) {
#pragma unroll
        for (int mi = 0; mi < 4; mi++)
#pragma unroll
            for (int i = 0; i < 4; i++)
                psum[mi][i] += __shfl_xor(psum[mi][i], st, 64);
    }
    float rinv[4][4];
#pragma unroll
    for (int mi = 0; mi < 4; mi++)
#pragma unroll
        for (int i = 0; i < 4; i++) rinv[mi][i] = 1.f / psum[mi][i];

    __syncthreads();  // all waves done reading sP (hidden) in phase A
    // write P (fp16) into sP: cols w*80 + nt*16 + arow, rows mi*16 + aq*4 + i
#pragma unroll
    for (int mi = 0; mi < 4; mi++)
#pragma unroll
        for (int nt = 0; nt < 5; nt++) {
            int col = w * 80 + nt * 16 + arow;
#pragma unroll
            for (int i = 0; i < 4; i++) {
                int r = mi * 16 + aq * 4 + i;
                *sp_ptr(sP, r, col) = (half_t)(acc[mi][nt][i] * rinv[mi][i]);
            }
        }
    __syncthreads();

    // ---- phase B: out[:, w*80 : w*80+80] = P @ Vo_b ----
    f4 acc2[4][5];
#pragma unroll
    for (int mi = 0; mi < 4; mi++)
#pragma unroll
        for (int nt = 0; nt < 5; nt++) acc2[mi][nt] = (f4){0.f, 0.f, 0.f, 0.f};
    for (int kb = 0; kb < 20; kb++) {
        h8 p[4];
#pragma unroll
        for (int mi = 0; mi < 4; mi++)
            p[mi] = *(const h8*)sp_ptr(sP, mi * 16 + arow, kb * 32 + aq * 8);
        h8 vf[5];
#pragma unroll
        for (int nt = 0; nt < 5; nt++)
            vf[nt] = *(const h8*)(pVb + ((size_t)((w * 5 + nt) * 20 + kb) * 64 + l) * 8);
        __builtin_amdgcn_s_setprio(1);
#pragma unroll
        for (int nt = 0; nt < 5; nt++)
#pragma unroll
            for (int mi = 0; mi < 4; mi++)
                acc2[mi][nt] = __builtin_amdgcn_mfma_f32_16x16x32_f16(p[mi], vf[nt], acc2[mi][nt], 0, 0, 0);
        __builtin_amdgcn_s_setprio(0);
    }
    float* Ob = out + ((size_t)b * NN + n0) * CC;
#pragma unroll
    for (int nt = 0; nt < 5; nt++) {
        int col = (w * 5 + nt) * 16 + arow;
        float bias = bo[col];
#pragma unroll
        for (int mi = 0; mi < 4; mi++)
#pragma unroll
            for (int i = 0; i < 4; i++) {
                int r = mi * 16 + aq * 4 + i;
                Ob[(size_t)r * CC + col] = acc2[mi][nt][i] + bias;
            }
    }
}

extern "C" void kernel_launch(void* const* d_in, const int* in_sizes, int n_in,
                              void* d_out, int out_size, void* d_ws, size_t ws_size,
                              hipStream_t stream) {
    const float* hidden = (const float*)d_in[0];
    const float* enc    = (const float*)d_in[1];
    const float* Wq     = (const float*)d_in[2];
    const float* Wk     = (const float*)d_in[3];
    const float* Wv     = (const float*)d_in[4];
    const float* Wo     = (const float*)d_in[5];
    const float* bo     = (const float*)d_in[6];
    const float* target = (const float*)d_in[7];
    const float* anchor = (const float*)d_in[8];
    const float* pres   = (const float*)d_in[9];
    float* outp = (float*)d_out;
    char* ws = (char*)d_ws;

    float* u_hat = (float*)(ws + 0);          // 77*640 f32   -> 197120
    float* wvec  = (float*)(ws + 197120);     // 77*640 f32   -> 394240
    float* ginv  = (float*)(ws + 394240);     // 77*4 f32 pad -> 395520
    float* kmat  = (float*)(ws + 395520);     // 616*640 f32  -> 1972480
    float* vmat  = (float*)(ws + 1972480);    // 616*640 f32  -> 3549440
    half_t* pW   = (half_t*)(ws + 3549440);   // 768*1280 f16 -> 5515520
    half_t* pWq  = (half_t*)(ws + 5515520);   // 8*40*3*64*8  -> 6498560
    half_t* pWo  = (half_t*)(ws + 6498560);   // 8*40*3*64*8  -> 7481600
    half_t* pM   = (half_t*)(ws + 7481600);   // 8*409600 f16 -> 14035200
    half_t* pV   = (half_t*)(ws + 14035200);  // 8*409600 f16 -> 20588800

    hipLaunchKernelGGL(wpack_all, dim3(1037), dim3(256), 0, stream, Wk, Wv, Wq, Wo,
                       target, anchor, pres, pW, pWq, pWo, u_hat, wvec, ginv);
    hipLaunchKernelGGL(kv_gemm, dim3(156), dim3(256), 0, stream, enc, pW, kmat, vmat);
    hipLaunchKernelGGL(erase_apply, dim3(154), dim3(256), 0, stream, vmat, pres, u_hat,
                       wvec, ginv);
    hipLaunchKernelGGL(hsgemm, dim3(128), dim3(512), 0, stream, kmat, vmat, pWq, pWo, pM, pV);
    hipLaunchKernelGGL(attn_main, dim3(512), dim3(512), 0, stream, hidden, pM, pV, bo, outp);
}